// Round 1
// 216.824 us; speedup vs baseline: 1.0168x; 1.0168x over previous
//
#include <hip/hip_runtime.h>

constexpr int BB   = 4;
constexpr int CCH  = 256;
constexpr int IDIM = 128;
constexpr int NAa  = 4096;
constexpr int NDd  = 16384;
constexpr int PAD  = 320;                 // aug dim 257 padded to 320
constexpr float NAinv = 1.0f / 4096.0f;

typedef __bf16 bf16x8 __attribute__((ext_vector_type(8)));
typedef float  f32x4  __attribute__((ext_vector_type(4)));

__device__ inline unsigned short f2bfu(float f) {
    unsigned u = __float_as_uint(f);
    u += 0x7FFFu + ((u >> 16) & 1u);      // RNE
    return (unsigned short)(u >> 16);
}

// ---- aim fp32 -> bf16 + per-(b,c) rowsum r. grid: BB*CCH blocks of 256 ----
__global__ __launch_bounds__(256) void k_conv(const float* __restrict__ aim,
                                              unsigned short* __restrict__ Abf,
                                              float* __restrict__ r) {
    const int row = blockIdx.x;
    const float* src = aim + (long)row * NAa;
    unsigned short* dst = Abf + (long)row * NAa;
    const int t = threadIdx.x;
    float s = 0.f;
    #pragma unroll
    for (int j = 0; j < 4; ++j) {
        const int e = (j * 256 + t) * 4;
        float4 v = *(const float4*)(src + e);
        s += v.x + v.y + v.z + v.w;
        ushort4 o; o.x = f2bfu(v.x); o.y = f2bfu(v.y); o.z = f2bfu(v.z); o.w = f2bfu(v.w);
        *(ushort4*)(dst + e) = o;
    }
    __shared__ float red[256];
    red[t] = s; __syncthreads();
    for (int st = 128; st > 0; st >>= 1) { if (t < st) red[t] += red[t + st]; __syncthreads(); }
    if (t == 0) r[row] = red[0];
}

// ---- Phat (256x320, bf16) and RhatT (320x320, bf16, TRANSPOSED: [c2][k]) ----
__global__ __launch_bounds__(256) void k_prep(const float* __restrict__ qw,
                                              const float* __restrict__ gw,
                                              const float* __restrict__ gb,
                                              const float* __restrict__ thw,
                                              const float* __restrict__ thb,
                                              const float* __restrict__ phw,
                                              const float* __restrict__ phb,
                                              unsigned short* __restrict__ Ph,
                                              unsigned short* __restrict__ Rt) {
    const int idx = blockIdx.x * 256 + threadIdx.x;
    if (idx < CCH * PAD) {
        const int o = idx / PAD, c = idx - o * PAD;
        float acc = 0.f;
        if (c <= 256) {
            for (int i = 0; i < IDIM; ++i)
                acc += qw[o * IDIM + i] * ((c < 256) ? gw[i * CCH + c] : gb[i]);
        }
        Ph[idx] = f2bfu(acc);
    } else {
        const int id2 = idx - CCH * PAD;
        const int c2 = id2 / PAD, k = id2 - c2 * PAD;   // row c2, col k (transposed)
        float acc = 0.f;
        if (k <= 256 && c2 <= 256) {
            for (int i = 0; i < IDIM; ++i) {
                const float av = (k < 256) ? thw[i * CCH + k] : thb[i];
                const float bv = (c2 < 256) ? phw[i * CCH + c2] : phb[i];
                acc += av * bv;
            }
        }
        Rt[id2] = f2bfu(acc);
    }
}

// ---- S partials: Spart[z] = A[b] @ A[b]^T over K-chunk. grid (4,4,BB*8), block 64 ----
__global__ __launch_bounds__(64) void k_S(const unsigned short* __restrict__ Abf,
                                          float* __restrict__ Spart) {
    const int z = blockIdx.z, b = z >> 3, chunk = z & 7;
    const unsigned short* A = Abf + (long)b * CCH * NAa;
    const int lane = threadIdx.x, quad = lane >> 4, l16 = lane & 15;
    const int mb = blockIdx.y * 64, nb = blockIdx.x * 64;
    const int kb = chunk * 512;
    f32x4 acc[4][4] = {};
    for (int ks = 0; ks < 16; ++ks) {
        const int k = kb + ks * 32 + quad * 8;
        bf16x8 af[4], bfr[4];
        #pragma unroll
        for (int i = 0; i < 4; ++i) af[i]  = *(const bf16x8*)(A + (long)(mb + i * 16 + l16) * NAa + k);
        #pragma unroll
        for (int j = 0; j < 4; ++j) bfr[j] = *(const bf16x8*)(A + (long)(nb + j * 16 + l16) * NAa + k);
        #pragma unroll
        for (int i = 0; i < 4; ++i)
            #pragma unroll
            for (int j = 0; j < 4; ++j)
                acc[i][j] = __builtin_amdgcn_mfma_f32_16x16x32_bf16(af[i], bfr[j], acc[i][j], 0, 0, 0);
    }
    float* o = Spart + (long)z * CCH * CCH;
    #pragma unroll
    for (int i = 0; i < 4; ++i)
        #pragma unroll
        for (int j = 0; j < 4; ++j)
            #pragma unroll
            for (int reg = 0; reg < 4; ++reg)
                o[(long)(mb + i * 16 + quad * 4 + reg) * CCH + nb + j * 16 + l16] = acc[i][j][reg];
}

// ---- assemble Shat (320x320 bf16, symmetric): [[sum Spart, r],[r^T, Na]] ----
__global__ __launch_bounds__(256) void k_red(const float* __restrict__ Spart,
                                             const float* __restrict__ r,
                                             unsigned short* __restrict__ Shat) {
    const int b = blockIdx.y;
    const int idx = blockIdx.x * 256 + threadIdx.x;     // < 320*320
    const int k = idx / PAD, n = idx - k * PAD;
    float v = 0.f;
    if (k < 256 && n < 256) {
        #pragma unroll
        for (int p = 0; p < 8; ++p)
            v += Spart[(long)(b * 8 + p) * CCH * CCH + k * CCH + n];
    } else if (k == 256 && n < 256) v = r[b * CCH + n];
    else if (n == 256 && k < 256)   v = r[b * CCH + k];
    else if (k == 256 && n == 256)  v = 4096.0f;
    Shat[(long)b * PAD * PAD + idx] = f2bfu(v);
}

// ---- That[b] = Phat @ Shat[b] (Shat symmetric -> B-frag reads rows). grid (5,4,BB), block 64 ----
__global__ __launch_bounds__(64) void k_t1(const unsigned short* __restrict__ Ph,
                                           const unsigned short* __restrict__ Sh,
                                           unsigned short* __restrict__ Th) {
    const int b = blockIdx.z;
    const unsigned short* S = Sh + (long)b * PAD * PAD;
    unsigned short* T = Th + (long)b * CCH * PAD;
    const int n0 = blockIdx.x * 64, m0 = blockIdx.y * 64;
    const int lane = threadIdx.x, quad = lane >> 4, l16 = lane & 15;
    f32x4 acc[4][4] = {};
    for (int kt = 0; kt < PAD; kt += 32) {
        bf16x8 af[4], bfr[4];
        #pragma unroll
        for (int i = 0; i < 4; ++i) af[i]  = *(const bf16x8*)(Ph + (long)(m0 + i * 16 + l16) * PAD + kt + quad * 8);
        #pragma unroll
        for (int j = 0; j < 4; ++j) bfr[j] = *(const bf16x8*)(S  + (long)(n0 + j * 16 + l16) * PAD + kt + quad * 8);
        #pragma unroll
        for (int i = 0; i < 4; ++i)
            #pragma unroll
            for (int j = 0; j < 4; ++j)
                acc[i][j] = __builtin_amdgcn_mfma_f32_16x16x32_bf16(af[i], bfr[j], acc[i][j], 0, 0, 0);
    }
    #pragma unroll
    for (int i = 0; i < 4; ++i)
        #pragma unroll
        for (int j = 0; j < 4; ++j)
            #pragma unroll
            for (int reg = 0; reg < 4; ++reg)
                T[(long)(m0 + i * 16 + quad * 4 + reg) * PAD + n0 + j * 16 + l16] = f2bfu(acc[i][j][reg]);
}

// ---- W5 = diag(s)/Na*(That@Rhat)+I (bf16); col 256 -> b5. grid (5,4,BB), block 64 ----
__global__ __launch_bounds__(64) void k_t2(const unsigned short* __restrict__ Th,
                                           const unsigned short* __restrict__ Rt,
                                           const float* __restrict__ qb,
                                           const float* __restrict__ gamma,
                                           const float* __restrict__ beta,
                                           const float* __restrict__ mean,
                                           const float* __restrict__ var,
                                           unsigned short* __restrict__ W5u,
                                           float* __restrict__ b5) {
    const int b = blockIdx.z;
    const unsigned short* A = Th + (long)b * CCH * PAD;
    const int n0 = blockIdx.x * 64, m0 = blockIdx.y * 64;
    const int lane = threadIdx.x, quad = lane >> 4, l16 = lane & 15;
    f32x4 acc[4][4] = {};
    for (int kt = 0; kt < PAD; kt += 32) {
        bf16x8 af[4], bfr[4];
        #pragma unroll
        for (int i = 0; i < 4; ++i) af[i]  = *(const bf16x8*)(A  + (long)(m0 + i * 16 + l16) * PAD + kt + quad * 8);
        #pragma unroll
        for (int j = 0; j < 4; ++j) bfr[j] = *(const bf16x8*)(Rt + (long)(n0 + j * 16 + l16) * PAD + kt + quad * 8);
        #pragma unroll
        for (int i = 0; i < 4; ++i)
            #pragma unroll
            for (int j = 0; j < 4; ++j)
                acc[i][j] = __builtin_amdgcn_mfma_f32_16x16x32_bf16(af[i], bfr[j], acc[i][j], 0, 0, 0);
    }
    #pragma unroll
    for (int i = 0; i < 4; ++i) {
        #pragma unroll
        for (int reg = 0; reg < 4; ++reg) {
            const int o = m0 + i * 16 + quad * 4 + reg;
            const float s = gamma[o] * rsqrtf(var[o] + 1e-5f);
            #pragma unroll
            for (int j = 0; j < 4; ++j) {
                const int c2 = n0 + j * 16 + l16;
                const float val = acc[i][j][reg] * s * NAinv;
                if (c2 < CCH)
                    W5u[((long)b * CCH + o) * CCH + c2] = f2bfu(val + (o == c2 ? 1.0f : 0.0f));
                else if (c2 == CCH)
                    b5[b * CCH + o] = val + s * (qb[o] - mean[o]) + beta[o];
            }
        }
    }
}

// ---- out = W5 @ detect + b5. Permuted-row LDS (conflict-free). ----
// v2: 2-deep staging register pipeline (xa/xb) + double-buffered W fragments so
// detect loads fly ~2 iterations and W (L2) loads cross the barrier in flight.
// grid (128, 2, BB), block 256
__global__ __launch_bounds__(256) void k_final(const float* __restrict__ D0,
                                               const unsigned short* __restrict__ W5u,
                                               const float* __restrict__ b5,
                                               float* __restrict__ out) {
    const int z = blockIdx.z;
    const int nb = blockIdx.x * 128;
    const int ob = blockIdx.y * 128;
    const float* D = D0 + (long)z * CCH * NDd;
    float* O = out + (long)z * CCH * NDd;
    const unsigned short* W = W5u + (long)z * CCH * CCH;
    const int t = threadIdx.x, wv = t >> 6, lane = t & 63, quad = lane >> 4, l16 = lane & 15;
    const int mw = (wv >> 1) * 64, nw = (wv & 1) * 64;
    const int r2 = t >> 4, g = t & 15;
    // logical row n -> physical row p = (n&7)*16 + (n>>3): write bank = (20g + r2)%32 (2-way, free)
    __shared__ __align__(16) unsigned short lb[2][128][40];

    f32x4 xa[4], xb[4];
    bf16x8 af[2][4], bfr[4];

    auto load_tile = [&](f32x4* x, int kt) {
        const float* base = D + (long)(kt + 2 * r2) * NDd + nb + 8 * g;
        x[0] = *(const f32x4*)(base);
        x[1] = *(const f32x4*)(base + NDd);
        x[2] = *(const f32x4*)(base + 4);
        x[3] = *(const f32x4*)(base + NDd + 4);
    };
    auto write_tile = [&](int buf, const f32x4* x) {
        #pragma unroll
        for (int e2 = 0; e2 < 2; ++e2)
            #pragma unroll
            for (int c = 0; c < 4; ++c) {
                const int n = 8 * g + 4 * e2 + c;
                const int p = ((n & 7) << 4) + (n >> 3);
                const unsigned v = (unsigned)f2bfu(x[2 * e2][c]) |
                                   ((unsigned)f2bfu(x[2 * e2 + 1][c]) << 16);
                *(unsigned*)&lb[buf][p][2 * r2] = v;
            }
    };
    auto loadW = [&](bf16x8* a, int kt) {
        #pragma unroll
        for (int i = 0; i < 4; ++i)
            a[i] = *(const bf16x8*)(W + (long)(ob + mw + i * 16 + l16) * CCH + kt + quad * 8);
    };

    int pj[4];
    #pragma unroll
    for (int j = 0; j < 4; ++j) {
        const int n = nw + j * 16 + l16;
        pj[j] = ((n & 7) << 4) + (n >> 3);
    }

    f32x4 acc[4][4] = {};
    // prologue: tiles 0,1 in flight; W frags for it=0 in flight; stage tile0; issue tile2
    load_tile(xa, 0);                       // tile 0
    load_tile(xb, 32);                      // tile 1
    loadW(af[0], 0);
    write_tile(0, xa);                      // stage tile 0 (waits only on xa)
    load_tile(xa, 64);                      // tile 2 (in flight ~2 iterations)
    #pragma unroll
    for (int it = 0; it < 8; ++it) {
        __syncthreads();
        const int kt = it * 32;
        #pragma unroll
        for (int j = 0; j < 4; ++j)
            bfr[j] = *(const bf16x8*)&lb[it & 1][pj[j]][quad * 8];
        #pragma unroll
        for (int i = 0; i < 4; ++i)
            #pragma unroll
            for (int j = 0; j < 4; ++j)
                acc[i][j] = __builtin_amdgcn_mfma_f32_16x16x32_bf16(af[it & 1][i], bfr[j], acc[i][j], 0, 0, 0);
        if (it < 7) {
            loadW(af[(it + 1) & 1], kt + 32);               // next W frags: cross barrier in flight
            write_tile((it + 1) & 1, (it & 1) ? xa : xb);   // stage tile it+1 (loaded 2 iters ago)
            if (it < 5) load_tile((it & 1) ? xa : xb, (it + 3) * 32);  // issue tile it+3
        }
    }
    #pragma unroll
    for (int i = 0; i < 4; ++i) {
        float bv[4];
        #pragma unroll
        for (int reg = 0; reg < 4; ++reg)
            bv[reg] = b5[z * CCH + ob + mw + i * 16 + quad * 4 + reg];
        #pragma unroll
        for (int j = 0; j < 4; ++j) {
            const int n = nb + nw + j * 16 + l16;
            #pragma unroll
            for (int reg = 0; reg < 4; ++reg)
                O[(long)(ob + mw + i * 16 + quad * 4 + reg) * NDd + n] = acc[i][j][reg] + bv[reg];
        }
    }
}

extern "C" void kernel_launch(void* const* d_in, const int* in_sizes, int n_in,
                              void* d_out, int out_size, void* d_ws, size_t ws_size,
                              hipStream_t stream) {
    const float* detect = (const float*)d_in[0];
    const float* aim    = (const float*)d_in[1];
    const float* g_w    = (const float*)d_in[2];
    const float* g_b    = (const float*)d_in[3];
    const float* th_w   = (const float*)d_in[4];
    const float* th_b   = (const float*)d_in[5];
    const float* phi_w  = (const float*)d_in[6];
    const float* phi_b  = (const float*)d_in[7];
    const float* q_w    = (const float*)d_in[8];
    const float* q_b    = (const float*)d_in[9];
    const float* gamma  = (const float*)d_in[10];
    const float* beta   = (const float*)d_in[11];
    const float* mean   = (const float*)d_in[12];
    const float* var    = (const float*)d_in[13];
    float* out = (float*)d_out;

    float* ws = (float*)d_ws;
    unsigned short* Abf = (unsigned short*)ws;              // 4,194,304 us = 2,097,152 f
    float* r     = ws + 2097152;                            // 1,024
    float* Spart = r + 1024;                                // 8*4*65536 = 2,097,152 f
    unsigned short* ub = (unsigned short*)(Spart + 2097152);
    unsigned short* Shat_u  = ub;                           // 4*320*320 = 409,600 us
    unsigned short* Phat_u  = Shat_u + 409600;              // 256*320   =  81,920 us
    unsigned short* RhatT_u = Phat_u + 81920;               // 320*320   = 102,400 us
    unsigned short* That_u  = RhatT_u + 102400;             // 4*256*320 = 327,680 us
    unsigned short* W5u     = That_u + 327680;              // 4*256*256 = 262,144 us
    float* b5 = (float*)(W5u + 262144);                     // 1,024 f   (total ~19.2 MB)

    k_prep<<<dim3((CCH * PAD + PAD * PAD) / 256), dim3(256), 0, stream>>>(
        q_w, g_w, g_b, th_w, th_b, phi_w, phi_b, Phat_u, RhatT_u);
    k_conv<<<dim3(BB * CCH), dim3(256), 0, stream>>>(aim, Abf, r);
    k_S<<<dim3(4, 4, BB * 8), dim3(64), 0, stream>>>(Abf, Spart);
    k_red<<<dim3(PAD * PAD / 256, BB), dim3(256), 0, stream>>>(Spart, r, Shat_u);
    k_t1<<<dim3(5, 4, BB), dim3(64), 0, stream>>>(Phat_u, Shat_u, That_u);
    k_t2<<<dim3(5, 4, BB), dim3(64), 0, stream>>>(That_u, RhatT_u, q_b, gamma, beta, mean, var, W5u, b5);
    k_final<<<dim3(NDd / 128, CCH / 128, BB), dim3(256), 0, stream>>>(detect, W5u, b5, out);
}